// Round 10
// baseline (174.065 us; speedup 1.0000x reference)
//
#include <hip/hip_runtime.h>
#include <hip/hip_bf16.h>
#include <stdint.h>

#define M_DIM 4096
#define N_DIM 4096
#define K_DIM 2048

typedef __bf16 bf16x8 __attribute__((ext_vector_type(8)));
typedef float f32x4 __attribute__((ext_vector_type(4)));
typedef unsigned short u16x8 __attribute__((ext_vector_type(8)));

// ---------------- fp32 -> bf16 (RNE) ----------------
__device__ __forceinline__ unsigned short f32_to_bf16(float f) {
  union { float f; unsigned int u; } c; c.f = f;
  unsigned int u = c.u;
  unsigned int r = (u + 0x7FFFu + ((u >> 16) & 1u)) >> 16;
  return (unsigned short)r;
}

// x: fp32->bf16 with the verified 64-col XOR granule swizzle (granule g of
//    row r holds source granule g ^ (r&7)) -> conflict-free LDS staging.
// W: fp32->bf16 packed in MFMA-FRAGMENT-MAJOR order so the GEMM loads
//    B-fragments straight from global, fully coalesced (lane-linear 16B):
//    wpk granule index = ((bn128*64 + ksg)*8 + i)*64 + lane holds
//    W[bn128*128 + i*16 + (lane&15)][ksg*32 + (lane>>4)*8 + 0..7].
// Block 0 zeroes S.
__global__ void __launch_bounds__(256) cvt_kernel(
    const float* __restrict__ x, const float* __restrict__ w,
    unsigned short* __restrict__ xb, unsigned short* __restrict__ wpk,
    float* __restrict__ S) {
  if (blockIdx.x == 0) {
#pragma unroll
    for (int k = 0; k < 16; ++k)
      S[threadIdx.x + k * 256] = 0.f;
  }

  const int nG = M_DIM * K_DIM / 8;  // 8-elt granules per tensor
  int i = blockIdx.x * 256 + threadIdx.x;
  if (i < nG) {
    // ---- x path (LDS-swizzled) ----
    const int row = i >> 8;        // K/8 = 256 granules per row
    const int cg  = i & 255;
    const int kt  = cg >> 3;
    const int g   = cg & 7;
    const int sg  = g ^ (row & 7);
    const float4* s4 = (const float4*)(x + (size_t)row * K_DIM + kt * 64 + sg * 8);
    float4 f0 = s4[0], f1 = s4[1];
    u16x8 o;
    o[0] = f32_to_bf16(f0.x); o[1] = f32_to_bf16(f0.y);
    o[2] = f32_to_bf16(f0.z); o[3] = f32_to_bf16(f0.w);
    o[4] = f32_to_bf16(f1.x); o[5] = f32_to_bf16(f1.y);
    o[6] = f32_to_bf16(f1.z); o[7] = f32_to_bf16(f1.w);
    ((u16x8*)xb)[i] = o;
  } else {
    // ---- W fragment-pack path ----
    const int og    = i - nG;            // output granule
    const int bn128 = og >> 15;          // 64*8*64 granules per 128-col group
    const int rem   = og & 32767;
    const int ksg   = rem >> 9;
    const int rem2  = rem & 511;
    const int fi    = rem2 >> 6;
    const int lane  = rem2 & 63;
    const int n  = bn128 * 128 + fi * 16 + (lane & 15);
    const int kg = ksg * 4 + (lane >> 4);
    const float4* s4 = (const float4*)(w + (size_t)n * K_DIM + kg * 8);
    float4 f0 = s4[0], f1 = s4[1];
    u16x8 o;
    o[0] = f32_to_bf16(f0.x); o[1] = f32_to_bf16(f0.y);
    o[2] = f32_to_bf16(f0.z); o[3] = f32_to_bf16(f0.w);
    o[4] = f32_to_bf16(f1.x); o[5] = f32_to_bf16(f1.y);
    o[6] = f32_to_bf16(f1.z); o[7] = f32_to_bf16(f1.w);
    ((u16x8*)wpk)[og] = o;   // contiguous 16B per thread: coalesced
  }
}

// ---------------- async global -> LDS, 16B per lane ----------------
__device__ __forceinline__ void gload_lds16(const unsigned short* g, unsigned short* l) {
  __builtin_amdgcn_global_load_lds(
      (const __attribute__((address_space(1))) unsigned int*)g,
      (__attribute__((address_space(3))) unsigned int*)l,
      16, 0, 0);
}

// Stage one 256x64 A-tile (4 calls; 512 lanes x 16B = 64 rows per call).
__device__ __forceinline__ void stage_A(const unsigned short* xg,
                                        unsigned short* lA, int k0) {
#pragma unroll
  for (int c = 0; c < 4; ++c)
    gload_lds16(xg + (size_t)(c * 64) * K_DIM + k0, lA + c * 64 * 64);
}

// ---------------- fused GEMM -> clamp -> sum exp(v-10) per row ----------------
// 256x256 block tile, 512 threads = 8 waves, wave tile 64x128 (4x8 frags of
// 16x16x32 bf16). A through double-buffered LDS (64 KB static, one barrier
// per kt, verified R8 swizzle). B-fragments load DIRECTLY from the packed
// global layout (lane-linear dwordx4, L1/L2-resident) - no LDS, no barrier
// dependency -> B loads fly during MFMA phases. Removes 2/3 of the LDS read
// pipe (R8: 59us = LDS 31us + MFMA 28us serialized).
// XCD swizzle: XCD x owns N-stripe {2x,2x+1} (its ~1MB of packed W stays in
// the 4 MiB per-XCD L2); A streams.
__global__ void __launch_bounds__(512, 2) gemm_lse_kernel(
    const unsigned short* __restrict__ xb,   // [M][K] bf16, swizzled granules
    const unsigned short* __restrict__ wpk,  // packed B fragments
    const float* __restrict__ bias,          // [N]
    float* __restrict__ S) {                 // [M] partial sums of exp(clamp(v)-10)
  __shared__ __align__(16) unsigned short As[32768];  // 2 x 256x64 (64 KB)

  const int tid = threadIdx.x;
  const int bid = blockIdx.x;
  const int bn_grp = (bid & 7) * 2 + ((bid >> 3) & 1);  // XCD-local N-stripe
  const int bm0 = (bid >> 4) * 256;
  const int bn0 = bn_grp * 256;

  const int wave = tid >> 6, lane = tid & 63;
  const int wr = (wave & 3) * 64;    // wave row offset (0..192)
  const int wc = (wave >> 2) * 128;  // wave col offset (0/128)
  const int lr = lane & 15;
  const int q  = lane >> 4;

  f32x4 acc[4][8];
  const f32x4 zero = {0.f, 0.f, 0.f, 0.f};
#pragma unroll
  for (int mi = 0; mi < 4; ++mi)
#pragma unroll
    for (int ni = 0; ni < 8; ++ni)
      acc[mi][ni] = zero;

  const int srow = tid >> 3;        // 0..63
  const int scol = (tid & 7) * 8;
  const unsigned short* xg = xb + (size_t)(bm0 + srow) * K_DIM + scol;
  unsigned short* lA = As + tid * 8;           // buf0 (+16384 shorts for buf1)

  // Packed-B base for this wave's column group (bn128 = bn0/128 + wc/128).
  const int bn128 = (bn0 + wc) >> 7;
  const unsigned short* wbase = wpk + ((size_t)bn128 << 18) + lane * 8;
  // fragment ptr = wbase + (ksg*8 + i)*512 elements, ksg = kt*2 + ks.

  stage_A(xg, lA, 0);                          // prologue: tile 0 -> buf0

  for (int kt = 0; kt < 32; ++kt) {
    const unsigned short* Asb = As + (kt & 1) * 16384;
    unsigned short* lAn = lA + ((kt & 1) ^ 1) * 16384;
    __syncthreads();  // drains DMA of tile kt (issued a full phase ago)
    if (kt + 1 < 32)
      stage_A(xg, lAn, (kt + 1) * 64);

    // Issue ALL 16 B-fragment loads for this kt upfront (coalesced 1KB
    // bursts, vmcnt-tracked) so they overlap the ks0 MFMA burst.
    bf16x8 bfr0[8], bfr1[8];
    const unsigned short* wk = wbase + (size_t)(kt * 2) * 8 * 512;
#pragma unroll
    for (int i = 0; i < 8; ++i)
      bfr0[i] = *(const bf16x8*)(wk + i * 512);
#pragma unroll
    for (int i = 0; i < 8; ++i)
      bfr1[i] = *(const bf16x8*)(wk + (8 + i) * 512);

#pragma unroll
    for (int ks = 0; ks < 2; ++ks) {
      const int swcol = ((ks * 4 + q) ^ (lr & 7)) * 8;
      bf16x8 af[4];
#pragma unroll
      for (int i = 0; i < 4; ++i)
        af[i] = *(const bf16x8*)(Asb + (wr + i * 16 + lr) * 64 + swcol);
#pragma unroll
      for (int mi = 0; mi < 4; ++mi)
#pragma unroll
        for (int ni = 0; ni < 8; ++ni)
          acc[mi][ni] = __builtin_amdgcn_mfma_f32_16x16x32_bf16(
              af[mi], ks ? bfr1[ni] : bfr0[ni], acc[mi][ni], 0, 0, 0);
    }
  }

  // Epilogue: bias + clamp + exp(v-10); reduce across 16 lanes (128 cols);
  // one fire-and-forget atomic per row per wave (32 contributions/row).
  float bv[8];
#pragma unroll
  for (int ni = 0; ni < 8; ++ni)
    bv[ni] = bias[bn0 + wc + ni * 16 + lr];

#pragma unroll
  for (int mi = 0; mi < 4; ++mi) {
#pragma unroll
    for (int reg = 0; reg < 4; ++reg) {
      float s = 0.f;
#pragma unroll
      for (int ni = 0; ni < 8; ++ni) {
        float v = acc[mi][ni][reg] + bv[ni];  // SCALE_FACTOR*2 == 1.0
        v = fminf(fmaxf(v, -10.f), 10.f);
        s += __expf(v - 10.f);
      }
      s += __shfl_xor(s, 1);
      s += __shfl_xor(s, 2);
      s += __shfl_xor(s, 4);
      s += __shfl_xor(s, 8);
      if (lr == 0)
        atomicAdd(&S[bm0 + wr + mi * 16 + q * 4 + reg], s);
    }
  }
}

// ---------------- finalize: lse = 10 + log(S); mish(lse) ----------------
__global__ void __launch_bounds__(256) finalize_kernel(const float* __restrict__ S,
                                                       float* __restrict__ out) {
  int i = blockIdx.x * blockDim.x + threadIdx.x;
  float lse = 10.0f + logf(S[i]);
  float sp = fmaxf(lse, 0.f) + log1pf(expf(-fabsf(lse)));  // stable softplus
  out[i] = lse * tanhf(sp);
}

extern "C" void kernel_launch(void* const* d_in, const int* in_sizes, int n_in,
                              void* d_out, int out_size, void* d_ws, size_t ws_size,
                              hipStream_t stream) {
  const float* x = (const float*)d_in[0];   // [4096, 2048]
  const float* W = (const float*)d_in[1];   // [4096, 2048]
  const float* b = (const float*)d_in[2];   // [4096]
  float* out = (float*)d_out;               // [4096]

  char* ws = (char*)d_ws;
  float* S = (float*)ws;                                       // 16 KB
  unsigned short* xb = (unsigned short*)(ws + 16384);          // 16 MB
  unsigned short* wpk = (unsigned short*)(ws + 16384 + (size_t)M_DIM * K_DIM * 2);

  const int nG2 = 2 * M_DIM * K_DIM / 8;  // both tensors, 8-elt granules
  cvt_kernel<<<nG2 / 256, 256, 0, stream>>>(x, W, xb, wpk, S);

  gemm_lse_kernel<<<256, 512, 0, stream>>>(xb, wpk, b, S);  // 16x16, 1/CU

  finalize_kernel<<<M_DIM / 256, 256, 0, stream>>>(S, out);
}

// Round 11
// 163.868 us; speedup vs baseline: 1.0622x; 1.0622x over previous
//
#include <hip/hip_runtime.h>
#include <hip/hip_bf16.h>
#include <stdint.h>

#define M_DIM 4096
#define N_DIM 4096
#define K_DIM 2048

typedef __bf16 bf16x8 __attribute__((ext_vector_type(8)));
typedef float f32x4 __attribute__((ext_vector_type(4)));
typedef unsigned short u16x8 __attribute__((ext_vector_type(8)));

// ---------------- fp32 -> bf16 (RNE) ----------------
__device__ __forceinline__ unsigned short f32_to_bf16(float f) {
  union { float f; unsigned int u; } c; c.f = f;
  unsigned int u = c.u;
  unsigned int r = (u + 0x7FFFu + ((u >> 16) & 1u)) >> 16;
  return (unsigned short)r;
}

// Convert BOTH tensors fp32->bf16 with the 32-col-tile XOR swizzle:
// granule g (16B) of row r within each 32-col K-tile holds source granule
// g ^ ((r>>1)&3).
// Bank math: a 32-col row = 64 B = 4 granule-slots; row r's slot base is
// (4r)%8 (even rows slots 0-3, odd rows 4-7). XOR on row bit 1 separates
// rows r and r+2 within a parity class -> fragment reads land 2 lanes/slot
// (free, m136). R9's (r>>2)&3 left r,r+2 colliding -> 6.3e6 conflicts.
// Block 0 additionally zeroes S.
__global__ void __launch_bounds__(256) cvt_swz_kernel(
    const float* __restrict__ x, const float* __restrict__ w,
    unsigned short* __restrict__ xb, unsigned short* __restrict__ wb,
    float* __restrict__ S) {
  if (blockIdx.x == 0) {
#pragma unroll
    for (int k = 0; k < 16; ++k)
      S[threadIdx.x + k * 256] = 0.f;
  }

  const int nG = M_DIM * K_DIM / 8;  // 8-elt granules per tensor
  int i = blockIdx.x * 256 + threadIdx.x;
  const float* src;
  unsigned short* dst;
  int gid;
  if (i < nG) { src = x; dst = xb; gid = i; }
  else        { src = w; dst = wb; gid = i - nG; }

  const int row = gid >> 8;        // K/8 = 256 granules per row
  const int cg  = gid & 255;
  const int kt  = cg >> 2;         // 32-col tile index (64 per row)
  const int g   = cg & 3;          // granule within tile
  const int sg  = g ^ ((row >> 1) & 3);   // corrected swizzle

  const float4* s4 = (const float4*)(src + (size_t)row * K_DIM + kt * 32 + sg * 8);
  float4 f0 = s4[0], f1 = s4[1];
  u16x8 o;
  o[0] = f32_to_bf16(f0.x); o[1] = f32_to_bf16(f0.y);
  o[2] = f32_to_bf16(f0.z); o[3] = f32_to_bf16(f0.w);
  o[4] = f32_to_bf16(f1.x); o[5] = f32_to_bf16(f1.y);
  o[6] = f32_to_bf16(f1.z); o[7] = f32_to_bf16(f1.w);
  ((u16x8*)dst)[gid] = o;
}

// ---------------- async global -> LDS, 16B per lane ----------------
__device__ __forceinline__ void gload_lds16(const unsigned short* g, unsigned short* l) {
  __builtin_amdgcn_global_load_lds(
      (const __attribute__((address_space(1))) unsigned int*)g,
      (__attribute__((address_space(3))) unsigned int*)l,
      16, 0, 0);
}

// Stage one 128x32 A-tile (2 calls) + 256x32 B-tile (4 calls); 256 lanes x
// 16B = 64 rows of [32 bf16] per call. xg/wg/lA/lB carry the per-thread
// offset (row tid>>2, granule tid&3 -> LDS addr = base + tid*16B, the
// linear map global_load_lds requires).
__device__ __forceinline__ void stage_tile(
    const unsigned short* xg, const unsigned short* wg,
    unsigned short* lA, unsigned short* lB, int k0) {
#pragma unroll
  for (int c = 0; c < 2; ++c)
    gload_lds16(xg + (size_t)(c * 64) * K_DIM + k0, lA + c * 64 * 32);
#pragma unroll
  for (int c = 0; c < 4; ++c)
    gload_lds16(wg + (size_t)(c * 64) * K_DIM + k0, lB + c * 64 * 32);
}

// One K=32 compute step: 4 A-frags + 8 B-frags (ds_read_b128) -> 32 MFMAs.
__device__ __forceinline__ void compute_tile(
    const unsigned short* As, const unsigned short* Bs,
    int wr, int wc, int lr, int q, f32x4 acc[4][8]) {
  // granule q of K=32; swizzled col = (q ^ ((lr>>1)&3)) * 8
  // ((row>>1)&3 == (lr>>1)&3 for all fragment rows: wr, 16*i are mult of 16)
  const int swcol = (q ^ ((lr >> 1) & 3)) * 8;
  bf16x8 af[4], bfr[8];
#pragma unroll
  for (int i = 0; i < 4; ++i)
    af[i]  = *(const bf16x8*)(As + (wr + i * 16 + lr) * 32 + swcol);
#pragma unroll
  for (int i = 0; i < 8; ++i)
    bfr[i] = *(const bf16x8*)(Bs + (wc + i * 16 + lr) * 32 + swcol);
#pragma unroll
  for (int mi = 0; mi < 4; ++mi)
#pragma unroll
    for (int ni = 0; ni < 8; ++ni)
      acc[mi][ni] = __builtin_amdgcn_mfma_f32_16x16x32_bf16(
          af[mi], bfr[ni], acc[mi][ni], 0, 0, 0);
}

// ---------------- fused GEMM -> clamp -> sum exp(v-10) per row ----------------
// 128x256 block tile, 256 threads = 4 waves, each wave 64x128 (4x8 frags).
// BK=32, double-buffered LDS (48 KB static), ONE barrier per K-step.
// TWO independent blocks per CU (512 blocks): independent barriers de-phase
// the read-burst/MFMA-burst cycles that phase-locked R8's single 8-wave
// block (59us = LDS 31 + MFMA 28 SERIAL; MfmaUtil 48%). R9 tested this
// with a broken swizzle (6.3e6 conflicts); this is the clean test.
// XCD swizzle: XCD x owns N-stripe {2x, 2x+1} -> its ~1 MB of B rows stays
// in the 4 MiB per-XCD L2 while A streams.
__global__ void __launch_bounds__(256, 2) gemm_lse_kernel(
    const unsigned short* __restrict__ xb,   // [M][K] bf16, swizzled granules
    const unsigned short* __restrict__ wb,   // [N][K] bf16, swizzled granules
    const float* __restrict__ bias,          // [N]
    float* __restrict__ S) {                 // [M] partial sums of exp(clamp(v)-10)
  __shared__ __align__(16) unsigned short lds[24576];  // 48 KB
  unsigned short* As0 = lds;            // 128*32
  unsigned short* Bs0 = lds + 4096;     // 256*32
  unsigned short* As1 = lds + 12288;
  unsigned short* Bs1 = lds + 16384;

  const int tid = threadIdx.x;
  const int bid = blockIdx.x;
  const int bn0 = ((bid & 7) * 2 + ((bid >> 3) & 1)) * 256;  // XCD-local
  const int bm0 = (bid >> 4) * 128;

  const int wave = tid >> 6, lane = tid & 63;
  const int wr = (wave & 1) * 64;    // wave row offset (0/64)
  const int wc = (wave >> 1) * 128;  // wave col offset (0/128)
  const int lr = lane & 15;
  const int q  = lane >> 4;

  f32x4 acc[4][8];
  const f32x4 zero = {0.f, 0.f, 0.f, 0.f};
#pragma unroll
  for (int mi = 0; mi < 4; ++mi)
#pragma unroll
    for (int ni = 0; ni < 8; ++ni)
      acc[mi][ni] = zero;

  const int srow = tid >> 2;        // 0..63
  const int scol = (tid & 3) * 8;   // granule within 32-col tile

  const unsigned short* xg = xb + (size_t)(bm0 + srow) * K_DIM + scol;
  const unsigned short* wg = wb + (size_t)(bn0 + srow) * K_DIM + scol;
  unsigned short* lA = lds + tid * 8;           // into As0 (+12288 for buf1)
  unsigned short* lB = lds + 4096 + tid * 8;    // into Bs0 (+12288 for buf1)

  stage_tile(xg, wg, lA, lB, 0);                // prologue: tile 0 -> buf0

  for (int kt = 0; kt < 64; kt += 2) {
    __syncthreads();  // drains DMA of tile kt (issued a full phase ago)
    if (kt + 1 < 64)
      stage_tile(xg, wg, lA + 12288, lB + 12288, (kt + 1) * 32);
    compute_tile(As0, Bs0, wr, wc, lr, q, acc);

    __syncthreads();
    if (kt + 2 < 64)
      stage_tile(xg, wg, lA, lB, (kt + 2) * 32);
    compute_tile(As1, Bs1, wr, wc, lr, q, acc);
  }

  // Epilogue: bias + clamp + exp(v-10); reduce across 16 lanes (128 cols);
  // one fire-and-forget atomic per row per wave (32 contributions/row).
  float bv[8];
#pragma unroll
  for (int ni = 0; ni < 8; ++ni)
    bv[ni] = bias[bn0 + wc + ni * 16 + lr];

#pragma unroll
  for (int mi = 0; mi < 4; ++mi) {
#pragma unroll
    for (int reg = 0; reg < 4; ++reg) {
      float s = 0.f;
#pragma unroll
      for (int ni = 0; ni < 8; ++ni) {
        float v = acc[mi][ni][reg] + bv[ni];  // SCALE_FACTOR*2 == 1.0
        v = fminf(fmaxf(v, -10.f), 10.f);
        s += __expf(v - 10.f);
      }
      s += __shfl_xor(s, 1);
      s += __shfl_xor(s, 2);
      s += __shfl_xor(s, 4);
      s += __shfl_xor(s, 8);
      if (lr == 0)
        atomicAdd(&S[bm0 + wr + mi * 16 + q * 4 + reg], s);
    }
  }
}

// ---------------- finalize: lse = 10 + log(S); mish(lse) ----------------
__global__ void __launch_bounds__(256) finalize_kernel(const float* __restrict__ S,
                                                       float* __restrict__ out) {
  int i = blockIdx.x * blockDim.x + threadIdx.x;
  float lse = 10.0f + logf(S[i]);
  float sp = fmaxf(lse, 0.f) + log1pf(expf(-fabsf(lse)));  // stable softplus
  out[i] = lse * tanhf(sp);
}

extern "C" void kernel_launch(void* const* d_in, const int* in_sizes, int n_in,
                              void* d_out, int out_size, void* d_ws, size_t ws_size,
                              hipStream_t stream) {
  const float* x = (const float*)d_in[0];   // [4096, 2048]
  const float* W = (const float*)d_in[1];   // [4096, 2048]
  const float* b = (const float*)d_in[2];   // [4096]
  float* out = (float*)d_out;               // [4096]

  char* ws = (char*)d_ws;
  float* S = (float*)ws;                                       // 16 KB
  unsigned short* xb = (unsigned short*)(ws + 16384);          // 16 MB
  unsigned short* wb = (unsigned short*)(ws + 16384 + (size_t)M_DIM * K_DIM * 2);

  const int nG2 = 2 * M_DIM * K_DIM / 8;  // both tensors, 8-elt granules
  cvt_swz_kernel<<<nG2 / 256, 256, 0, stream>>>(x, W, xb, wb, S);

  gemm_lse_kernel<<<512, 256, 0, stream>>>(xb, wb, b, S);  // 2 blocks/CU

  finalize_kernel<<<M_DIM / 256, 256, 0, stream>>>(S, out);
}